// Round 10
// baseline (126.899 us; speedup 1.0000x reference)
//
#include <hip/hip_runtime.h>
#include <hip/hip_fp16.h>

// ACmix: b=2, C=64 (HEAD=4 x HEAD_DIM=16), (d,w,h)=(8,32,32), L=8192
// Attention view: (H2,W2)=(64,128). Conv view: (8, 1024). K_ATT=7 PAD=3.
//
// R10: end-to-end f16 packing through global ws.
//   qkvf: block 256 thr = 4 waves; wave owns hd PAIR (2w,2w+1) of its half;
//         thread owns 2 l.  Writes q*0.25, kp=k-pe, v, f ALL as __half2
//         packed channel pairs (thread holds both pair members -> direct
//         pack, no exchange).  pe computed here (qkvf knows l).
//   att : staging = pure 2-dword copy per (pixel, ch-pair); q = 4 dwords.
//   conv: reads packed f, extracts parity (g*9+i)&1.

static __device__ __forceinline__ float2 h2f2(float w) {
    __half2 h = *reinterpret_cast<__half2*>(&w);
    return __half22float2(h);
}
static __device__ __forceinline__ float pack2(float a, float b) {
    __half2 h = __floats2half2_rn(a, b);
    return *reinterpret_cast<float*>(&h);
}

// ---------------------------------------------------------------------------
// Kernel 1: q/k/v 1x1 convs + fc, f16-packed outputs.
// Grid 256 = b(2) x half(2) x ltile(64 tiles of 128 l); 256 thr (2 blk/CU).
// ---------------------------------------------------------------------------
__global__ __launch_bounds__(256) void qkvf_kernel(
    const float* __restrict__ x,
    const float* __restrict__ w1, const float* __restrict__ b1,
    const float* __restrict__ w2, const float* __restrict__ b2,
    const float* __restrict__ w3, const float* __restrict__ b3,
    const float* __restrict__ wfc,
    const float* __restrict__ wp, const float* __restrict__ bp,
    float* __restrict__ q16, float* __restrict__ kp16,
    float* __restrict__ v16, float* __restrict__ f16p)
{
    __shared__ float xs[64][128];       // [ci][l]            32 KB
    __shared__ float wlds[3][32][64];   // [mat][c_local][ci] 24 KB

    int bx    = blockIdx.x;
    int ltile = bx & 63;
    int half  = (bx >> 6) & 1;
    int b     = bx >> 7;
    int l0    = ltile * 128;
    int hdb   = half * 8;

    for (int t = threadIdx.x; t < 1536; t += 256) {
        int mat = t >> 9;
        int r   = t & 511;
        int cl  = r >> 4;              // hh*8 + hdl
        int col = r & 15;
        int hh = cl >> 3, hdl = cl & 7;
        int c  = hh * 16 + hdb + hdl;
        const float* src = (mat == 0) ? w1 : (mat == 1) ? w2 : w3;
        ((float4*)wlds)[t] = ((const float4*)src)[c * 16 + col];
    }
    const float4* xg = (const float4*)(x + (size_t)b * 64 * 8192);
    for (int t = threadIdx.x; t < 2048; t += 256) {
        int ci = t >> 5, col = t & 31;
        ((float4*)xs)[t] = xg[ci * 2048 + (l0 >> 2) + col];
    }
    __syncthreads();

    int lane = threadIdx.x & 63;
    int wv   = __builtin_amdgcn_readfirstlane(threadIdx.x >> 6); // 0..3
    int ll   = 2 * lane;

    // acc[hh][p][l01]
    float qa[4][2][2], ka[4][2][2], va[4][2][2];
#pragma unroll
    for (int hh = 0; hh < 4; ++hh)
#pragma unroll
        for (int p = 0; p < 2; ++p) {
            int c = hh * 16 + hdb + 2 * wv + p;
            qa[hh][p][0] = qa[hh][p][1] = b1[c];
            ka[hh][p][0] = ka[hh][p][1] = b2[c];
            va[hh][p][0] = va[hh][p][1] = b3[c];
        }

#pragma unroll 4
    for (int c4 = 0; c4 < 16; ++c4) {
        float2 xv[4];
#pragma unroll
        for (int u = 0; u < 4; ++u)
            xv[u] = *(const float2*)&xs[c4 * 4 + u][ll];
#pragma unroll
        for (int hh = 0; hh < 4; ++hh)
#pragma unroll
            for (int p = 0; p < 2; ++p) {
                int cl = hh * 8 + 2 * wv + p;
                float4 wq = *(const float4*)&wlds[0][cl][c4 * 4];
                float4 wk = *(const float4*)&wlds[1][cl][c4 * 4];
                float4 wx = *(const float4*)&wlds[2][cl][c4 * 4];
                qa[hh][p][0] = fmaf(wq.x, xv[0].x, qa[hh][p][0]);
                qa[hh][p][1] = fmaf(wq.x, xv[0].y, qa[hh][p][1]);
                qa[hh][p][0] = fmaf(wq.y, xv[1].x, qa[hh][p][0]);
                qa[hh][p][1] = fmaf(wq.y, xv[1].y, qa[hh][p][1]);
                qa[hh][p][0] = fmaf(wq.z, xv[2].x, qa[hh][p][0]);
                qa[hh][p][1] = fmaf(wq.z, xv[2].y, qa[hh][p][1]);
                qa[hh][p][0] = fmaf(wq.w, xv[3].x, qa[hh][p][0]);
                qa[hh][p][1] = fmaf(wq.w, xv[3].y, qa[hh][p][1]);

                ka[hh][p][0] = fmaf(wk.x, xv[0].x, ka[hh][p][0]);
                ka[hh][p][1] = fmaf(wk.x, xv[0].y, ka[hh][p][1]);
                ka[hh][p][0] = fmaf(wk.y, xv[1].x, ka[hh][p][0]);
                ka[hh][p][1] = fmaf(wk.y, xv[1].y, ka[hh][p][1]);
                ka[hh][p][0] = fmaf(wk.z, xv[2].x, ka[hh][p][0]);
                ka[hh][p][1] = fmaf(wk.z, xv[2].y, ka[hh][p][1]);
                ka[hh][p][0] = fmaf(wk.w, xv[3].x, ka[hh][p][0]);
                ka[hh][p][1] = fmaf(wk.w, xv[3].y, ka[hh][p][1]);

                va[hh][p][0] = fmaf(wx.x, xv[0].x, va[hh][p][0]);
                va[hh][p][1] = fmaf(wx.x, xv[0].y, va[hh][p][1]);
                va[hh][p][0] = fmaf(wx.y, xv[1].x, va[hh][p][0]);
                va[hh][p][1] = fmaf(wx.y, xv[1].y, va[hh][p][1]);
                va[hh][p][0] = fmaf(wx.z, xv[2].x, va[hh][p][0]);
                va[hh][p][1] = fmaf(wx.z, xv[2].y, va[hh][p][1]);
                va[hh][p][0] = fmaf(wx.w, xv[3].x, va[hh][p][0]);
                va[hh][p][1] = fmaf(wx.w, xv[3].y, va[hh][p][1]);
            }
    }

    // ---- coords for pe at l and l+1 (ll even: no carry into ww/dd) ----
    int l  = l0 + ll;
    int dd = l >> 10, r2c = l & 1023, ww2 = r2c >> 5, hh2 = r2c & 31;
    float ld  = dd  * (2.0f / 7.0f)  - 1.0f;
    float lw  = ww2 * (2.0f / 31.0f) - 1.0f;
    float lh0 = hh2 * (2.0f / 31.0f) - 1.0f;
    float lh1 = (hh2 + 1) * (2.0f / 31.0f) - 1.0f;

    // ---- packed stores: q, kp, v ----
#pragma unroll
    for (int hh = 0; hh < 4; ++hh) {
        int c0  = hh * 16 + hdb + 2 * wv;       // even channel of pair
        int row = b * 32 + (c0 >> 1);
        size_t o = (size_t)row * 8192 + l;

        *(float2*)&q16[o] = make_float2(
            pack2(qa[hh][0][0] * 0.25f, qa[hh][1][0] * 0.25f),
            pack2(qa[hh][0][1] * 0.25f, qa[hh][1][1] * 0.25f));

        float pe00 = bp[c0];
        pe00 = fmaf(wp[c0 * 3 + 0], ld, pe00);
        pe00 = fmaf(wp[c0 * 3 + 1], lw, pe00);
        float pe01 = fmaf(wp[c0 * 3 + 2], lh1, pe00);
        pe00 = fmaf(wp[c0 * 3 + 2], lh0, pe00);
        float pe10 = bp[c0 + 1];
        pe10 = fmaf(wp[c0 * 3 + 3], ld, pe10);
        pe10 = fmaf(wp[c0 * 3 + 4], lw, pe10);
        float pe11 = fmaf(wp[c0 * 3 + 5], lh1, pe10);
        pe10 = fmaf(wp[c0 * 3 + 5], lh0, pe10);

        *(float2*)&kp16[o] = make_float2(
            pack2(ka[hh][0][0] - pe00, ka[hh][1][0] - pe10),
            pack2(ka[hh][0][1] - pe01, ka[hh][1][1] - pe11));

        *(float2*)&v16[o] = make_float2(
            pack2(va[hh][0][0], va[hh][1][0]),
            pack2(va[hh][0][1], va[hh][1][1]));
    }

    // ---- f (packed c144 pairs): t = m*8 + half*4 + wv ----
#pragma unroll
    for (int m = 0; m < 9; ++m) {
        float f00 = 0.f, f01 = 0.f, f10 = 0.f, f11 = 0.f;
#pragma unroll
        for (int hh = 0; hh < 4; ++hh) {
            float wq = wfc[m * 12 + 0 + hh];
            float wk = wfc[m * 12 + 4 + hh];
            float wx = wfc[m * 12 + 8 + hh];
            f00 = fmaf(wq, qa[hh][0][0], f00);
            f01 = fmaf(wq, qa[hh][0][1], f01);
            f10 = fmaf(wq, qa[hh][1][0], f10);
            f11 = fmaf(wq, qa[hh][1][1], f11);
            f00 = fmaf(wk, ka[hh][0][0], f00);
            f01 = fmaf(wk, ka[hh][0][1], f01);
            f10 = fmaf(wk, ka[hh][1][0], f10);
            f11 = fmaf(wk, ka[hh][1][1], f11);
            f00 = fmaf(wx, va[hh][0][0], f00);
            f01 = fmaf(wx, va[hh][0][1], f01);
            f10 = fmaf(wx, va[hh][1][0], f10);
            f11 = fmaf(wx, va[hh][1][1], f11);
        }
        int t = m * 8 + half * 4 + wv;
        size_t o = (size_t)(b * 72 + t) * 8192 + l;
        *(float2*)&f16p[o] = make_float2(pack2(f00, f10), pack2(f01, f11));
    }
}

// ---------------------------------------------------------------------------
// Kernel 2: attention branch.  out = rate1 * out_att.
// Staging = pure packed-dword copy (kp already has pe folded in).
// LDS: kp/vt __half2, pixel stride 12 dwords (b128-aligned, conflict-free).
// ---------------------------------------------------------------------------
__global__ __launch_bounds__(512, 4) void att_kernel(
    const float* __restrict__ q16, const float* __restrict__ kp16,
    const float* __restrict__ v16,
    const float* __restrict__ rate1p, float* __restrict__ out)
{
    __shared__ float kpb[484 * 12];   // 23.2 KB
    __shared__ float vtb[484 * 12];   // 23.2 KB

    int bx = blockIdx.x;          // 8 n * 4 yt * 8 xt = 256
    int xt = bx & 7;
    int yt = (bx >> 3) & 3;
    int n  = bx >> 5;
    int head = n & 3;
    int b    = n >> 2;
    int y0 = yt * 16, x0 = xt * 16;

    // ---- stage: e = px(484) x c2(8), 2 dwords each ----
    for (int e = threadIdx.x; e < 3872; e += 512) {
        int c2 = e & 7;
        int px = e >> 3;
        int ty = px / 22, tx = px % 22;
        int sy = y0 + ty - 3; if (sy < 0) sy = -sy; else if (sy >= 64)  sy = 126 - sy;
        int sx = x0 + tx - 3; if (sx < 0) sx = -sx; else if (sx >= 128) sx = 254 - sx;
        int l = sy * 128 + sx;
        size_t o = (size_t)(b * 32 + head * 8 + c2) * 8192 + l;
        kpb[px * 12 + c2] = kp16[o];
        vtb[px * 12 + c2] = v16[o];
    }
    __syncthreads();

    int pix  = threadIdx.x >> 1;      // 0..255
    int part = threadIdx.x & 1;       // channel half
    int tx = pix & 15, ty = pix >> 4;
    int l = (y0 + ty) * 128 + (x0 + tx);
    int cb = part * 8;                // channel base

    float qc[8];
#pragma unroll
    for (int j = 0; j < 4; ++j) {
        float w = q16[(size_t)(b * 32 + head * 8 + part * 4 + j) * 8192 + l];
        float2 u = h2f2(w);
        qc[2 * j] = u.x; qc[2 * j + 1] = u.y;
    }

    float lg[49];
#pragma unroll
    for (int i = 0; i < 7; ++i)
#pragma unroll
        for (int j = 0; j < 7; ++j) {
            float4 r = *(const float4*)&kpb[((ty + i) * 22 + tx + j) * 12
                                            + part * 4];
            float2 u0 = h2f2(r.x), u1 = h2f2(r.y),
                   u2 = h2f2(r.z), u3 = h2f2(r.w);
            float acc =      qc[0] * u0.x;
            acc = fmaf(qc[1], u0.y, acc); acc = fmaf(qc[2], u1.x, acc);
            acc = fmaf(qc[3], u1.y, acc); acc = fmaf(qc[4], u2.x, acc);
            acc = fmaf(qc[5], u2.y, acc); acc = fmaf(qc[6], u3.x, acc);
            acc = fmaf(qc[7], u3.y, acc);
            lg[i * 7 + j] = acc;
        }
#pragma unroll
    for (int kk = 0; kk < 49; ++kk)
        lg[kk] += __shfl_xor(lg[kk], 1, 64);

    float mx = lg[0];
#pragma unroll
    for (int kk = 1; kk < 49; ++kk) mx = fmaxf(mx, lg[kk]);
    float se = 0.f;
#pragma unroll
    for (int kk = 0; kk < 49; ++kk) { lg[kk] = __expf(lg[kk] - mx); se += lg[kk]; }
    float scale = rate1p[0] / se;

    float oc[8];
#pragma unroll
    for (int c = 0; c < 8; ++c) oc[c] = 0.f;
#pragma unroll
    for (int i = 0; i < 7; ++i)
#pragma unroll
        for (int j = 0; j < 7; ++j) {
            float wgt = lg[i * 7 + j];
            float4 r = *(const float4*)&vtb[((ty + i) * 22 + tx + j) * 12
                                            + part * 4];
            float2 u0 = h2f2(r.x), u1 = h2f2(r.y),
                   u2 = h2f2(r.z), u3 = h2f2(r.w);
            oc[0] = fmaf(wgt, u0.x, oc[0]); oc[1] = fmaf(wgt, u0.y, oc[1]);
            oc[2] = fmaf(wgt, u1.x, oc[2]); oc[3] = fmaf(wgt, u1.y, oc[3]);
            oc[4] = fmaf(wgt, u2.x, oc[4]); oc[5] = fmaf(wgt, u2.y, oc[5]);
            oc[6] = fmaf(wgt, u3.x, oc[6]); oc[7] = fmaf(wgt, u3.y, oc[7]);
        }

#pragma unroll
    for (int c = 0; c < 8; ++c)
        out[(size_t)(b * 64 + head * 16 + cb + c) * 8192 + l] = oc[c] * scale;
}

// ---------------------------------------------------------------------------
// Kernel 3: conv branch + combine.  Reads packed f16 f; compute unchanged.
// 512 blocks (64-wide x-tiles) -> 2 blocks/CU, 8 waves/CU.
// ---------------------------------------------------------------------------
__global__ __launch_bounds__(256) void conv_kernel(
    const float* __restrict__ f16p,
    const float* __restrict__ wdep, const float* __restrict__ bdep,
    const float* __restrict__ rate2p, float* __restrict__ out)
{
    __shared__ float ft[9][8][66];

    int bx = blockIdx.x;          // 2 b * 16 g * 16 xt = 512
    int xt = bx & 15;
    int g  = (bx >> 4) & 15;
    int b  = bx >> 8;
    int x0 = xt * 64;

    const int NE = 9 * 8 * 66;    // 4752
    for (int e = threadIdx.x; e < NE; e += 256) {
        int xx  = e % 66;
        int rem = e / 66;
        int y = rem % 8, i = rem / 8;
        int gx = x0 + xx - 1;
        float val = 0.f;
        if (gx >= 0 && gx < 1024) {
            int c144 = g * 9 + i;
            float wd = f16p[(size_t)(b * 72 + (c144 >> 1)) * 8192
                            + y * 1024 + gx];
            float2 u = h2f2(wd);
            val = (c144 & 1) ? u.y : u.x;
        }
        ft[i][y][xx] = val;
    }
    __syncthreads();

    int xl = threadIdx.x & 63;
    int op = __builtin_amdgcn_readfirstlane(threadIdx.x >> 6); // wave id 0..3
    int o  = g * 4 + op;
    float rate2 = rate2p[0];

    float acc[8];
#pragma unroll
    for (int y = 0; y < 8; ++y) acc[y] = 0.f;

    for (int i = 0; i < 9; ++i) {
        float fr[10][3];
#pragma unroll
        for (int dx = 0; dx < 3; ++dx) { fr[0][dx] = 0.f; fr[9][dx] = 0.f; }
#pragma unroll
        for (int y = 0; y < 8; ++y)
#pragma unroll
            for (int dx = 0; dx < 3; ++dx)
                fr[y + 1][dx] = ft[i][y][xl + dx];
#pragma unroll
        for (int ky = 0; ky < 3; ++ky)
#pragma unroll
            for (int kx = 0; kx < 3; ++kx) {
                float wvv = wdep[((o * 9 + i) * 3 + ky) * 3 + kx];
#pragma unroll
                for (int y = 0; y < 8; ++y)
                    acc[y] = fmaf(wvv, fr[y + ky][kx], acc[y]);
            }
    }

    float bd = bdep[o];
#pragma unroll
    for (int y = 0; y < 8; ++y) {
        size_t idx = (size_t)(b * 64 + o) * 8192 + y * 1024 + x0 + xl;
        out[idx] = out[idx] + rate2 * (acc[y] + bd);
    }
}

// ---------------------------------------------------------------------------
extern "C" void kernel_launch(void* const* d_in, const int* in_sizes, int n_in,
                              void* d_out, int out_size, void* d_ws, size_t ws_size,
                              hipStream_t stream)
{
    (void)in_sizes; (void)n_in; (void)out_size; (void)ws_size;
    const float* x     = (const float*)d_in[0];
    const float* w1    = (const float*)d_in[1];
    const float* b1    = (const float*)d_in[2];
    const float* w2    = (const float*)d_in[3];
    const float* b2    = (const float*)d_in[4];
    const float* w3    = (const float*)d_in[5];
    const float* b3    = (const float*)d_in[6];
    const float* wp    = (const float*)d_in[7];
    const float* bp    = (const float*)d_in[8];
    const float* wfc   = (const float*)d_in[9];
    const float* wdep  = (const float*)d_in[10];
    const float* bdep  = (const float*)d_in[11];
    const float* rate1 = (const float*)d_in[12];
    const float* rate2 = (const float*)d_in[13];
    float* out = (float*)d_out;

    float* wsf  = (float*)d_ws;
    float* q16  = wsf;                 // 2*32*8192 = 524288 dwords
    float* kp16 = wsf + 524288;
    float* v16  = wsf + 1048576;
    float* f16p = wsf + 1572864;       // 2*72*8192 = 1179648 dwords

    qkvf_kernel<<<256, 256, 0, stream>>>(x, w1, b1, w2, b2, w3, b3, wfc,
                                         wp, bp, q16, kp16, v16, f16p);
    att_kernel <<<256, 512, 0, stream>>>(q16, kp16, v16, rate1, out);
    conv_kernel<<<512, 256, 0, stream>>>(f16p, wdep, bdep, rate2, out);
}

// Round 11
// 120.412 us; speedup vs baseline: 1.0539x; 1.0539x over previous
//
#include <hip/hip_runtime.h>
#include <hip/hip_fp16.h>

// ACmix: b=2, C=64 (HEAD=4 x HEAD_DIM=16), (d,w,h)=(8,32,32), L=8192
// Attention view: (H2,W2)=(64,128). Conv view: (8, 1024). K_ATT=7 PAD=3.
//
// R11 = exact revert to R9 (measured best, 118.9 us):
//   3 dispatches; qkvf 512-thr (wave owns one hd, 8-FMA-per-weight-read),
//   att 512-thr f16-packed LDS (2 thr/pixel), conv 512-block.
// R10's end-to-end f16 ws packing regressed (+8 us: qkvf register pressure
// + conv unpack).  R5/R8 fusion regressed (LDS-serialized 1 block/CU).
// Remaining dur is harness floor: 268 MB ws re-poison (~43 us) + input
// restores + launch gaps (~45 us) vs ~25 us of kernels.

static __device__ __forceinline__ float2 h2f2(float w) {
    __half2 h = *reinterpret_cast<__half2*>(&w);
    return __half22float2(h);
}

// ---------------------------------------------------------------------------
// Kernel 1: fused q/k/v 1x1 convs + fc (f_all).
// Weights in LDS, wave-uniform ds_read_b128 broadcast; wave owns one hd;
// thread owns 2 l.  Grid 256 = b(2) x half(2) x ltile(64).
// ---------------------------------------------------------------------------
__global__ __launch_bounds__(512) void qkvf_kernel(
    const float* __restrict__ x,
    const float* __restrict__ w1, const float* __restrict__ b1,
    const float* __restrict__ w2, const float* __restrict__ b2,
    const float* __restrict__ w3, const float* __restrict__ b3,
    const float* __restrict__ wfc,
    float* __restrict__ q, float* __restrict__ k, float* __restrict__ v,
    float* __restrict__ f)
{
    __shared__ float xs[64][128];       // [ci][l]            32 KB
    __shared__ float wlds[3][32][64];   // [mat][c_local][ci] 24 KB

    int bx    = blockIdx.x;
    int ltile = bx & 63;
    int half  = (bx >> 6) & 1;
    int b     = bx >> 7;
    int l0    = ltile * 128;
    int hdb   = half * 8;

    for (int t = threadIdx.x; t < 1536; t += 512) {
        int mat = t >> 9;
        int r   = t & 511;
        int cl  = r >> 4;
        int col = r & 15;
        int hh = cl >> 3, hdl = cl & 7;
        int c  = hh * 16 + hdb + hdl;
        const float* src = (mat == 0) ? w1 : (mat == 1) ? w2 : w3;
        ((float4*)wlds)[t] = ((const float4*)src)[c * 16 + col];
    }
    const float4* xg = (const float4*)(x + (size_t)b * 64 * 8192);
    for (int t = threadIdx.x; t < 2048; t += 512) {
        int ci = t >> 5, col = t & 31;
        ((float4*)xs)[t] = xg[ci * 2048 + (l0 >> 2) + col];
    }
    __syncthreads();

    int lane = threadIdx.x & 63;
    int wv   = __builtin_amdgcn_readfirstlane(threadIdx.x >> 6);
    int hd   = hdb + wv;
    int ll   = 2 * lane;

    float qa[4][2], ka[4][2], va[4][2];
#pragma unroll
    for (int hh = 0; hh < 4; ++hh) {
        int c = hh * 16 + hd;
        qa[hh][0] = qa[hh][1] = b1[c];
        ka[hh][0] = ka[hh][1] = b2[c];
        va[hh][0] = va[hh][1] = b3[c];
    }

#pragma unroll 4
    for (int c4 = 0; c4 < 16; ++c4) {
        float2 xv[4];
#pragma unroll
        for (int u = 0; u < 4; ++u)
            xv[u] = *(const float2*)&xs[c4 * 4 + u][ll];
#pragma unroll
        for (int hh = 0; hh < 4; ++hh) {
            int cl = hh * 8 + wv;
            float4 wq = *(const float4*)&wlds[0][cl][c4 * 4];
            float4 wk = *(const float4*)&wlds[1][cl][c4 * 4];
            float4 wx = *(const float4*)&wlds[2][cl][c4 * 4];
            qa[hh][0] = fmaf(wq.x, xv[0].x, qa[hh][0]);
            qa[hh][1] = fmaf(wq.x, xv[0].y, qa[hh][1]);
            qa[hh][0] = fmaf(wq.y, xv[1].x, qa[hh][0]);
            qa[hh][1] = fmaf(wq.y, xv[1].y, qa[hh][1]);
            qa[hh][0] = fmaf(wq.z, xv[2].x, qa[hh][0]);
            qa[hh][1] = fmaf(wq.z, xv[2].y, qa[hh][1]);
            qa[hh][0] = fmaf(wq.w, xv[3].x, qa[hh][0]);
            qa[hh][1] = fmaf(wq.w, xv[3].y, qa[hh][1]);

            ka[hh][0] = fmaf(wk.x, xv[0].x, ka[hh][0]);
            ka[hh][1] = fmaf(wk.x, xv[0].y, ka[hh][1]);
            ka[hh][0] = fmaf(wk.y, xv[1].x, ka[hh][0]);
            ka[hh][1] = fmaf(wk.y, xv[1].y, ka[hh][1]);
            ka[hh][0] = fmaf(wk.z, xv[2].x, ka[hh][0]);
            ka[hh][1] = fmaf(wk.z, xv[2].y, ka[hh][1]);
            ka[hh][0] = fmaf(wk.w, xv[3].x, ka[hh][0]);
            ka[hh][1] = fmaf(wk.w, xv[3].y, ka[hh][1]);

            va[hh][0] = fmaf(wx.x, xv[0].x, va[hh][0]);
            va[hh][1] = fmaf(wx.x, xv[0].y, va[hh][1]);
            va[hh][0] = fmaf(wx.y, xv[1].x, va[hh][0]);
            va[hh][1] = fmaf(wx.y, xv[1].y, va[hh][1]);
            va[hh][0] = fmaf(wx.z, xv[2].x, va[hh][0]);
            va[hh][1] = fmaf(wx.z, xv[2].y, va[hh][1]);
            va[hh][0] = fmaf(wx.w, xv[3].x, va[hh][0]);
            va[hh][1] = fmaf(wx.w, xv[3].y, va[hh][1]);
        }
    }

#pragma unroll
    for (int hh = 0; hh < 4; ++hh) {
        int c = hh * 16 + hd;
        size_t o = (size_t)(b * 64 + c) * 8192 + l0 + ll;
        *(float2*)&q[o] = make_float2(qa[hh][0] * 0.25f, qa[hh][1] * 0.25f);
        *(float2*)&k[o] = make_float2(ka[hh][0], ka[hh][1]);
        *(float2*)&v[o] = make_float2(va[hh][0], va[hh][1]);
    }

#pragma unroll
    for (int m = 0; m < 9; ++m) {
        float a0 = 0.f, a1 = 0.f;
#pragma unroll
        for (int hh = 0; hh < 4; ++hh) {
            a0 = fmaf(wfc[m * 12 + 0 + hh], qa[hh][0], a0);
            a1 = fmaf(wfc[m * 12 + 0 + hh], qa[hh][1], a1);
            a0 = fmaf(wfc[m * 12 + 4 + hh], ka[hh][0], a0);
            a1 = fmaf(wfc[m * 12 + 4 + hh], ka[hh][1], a1);
            a0 = fmaf(wfc[m * 12 + 8 + hh], va[hh][0], a0);
            a1 = fmaf(wfc[m * 12 + 8 + hh], va[hh][1], a1);
        }
        size_t o = ((size_t)(b * 9 + m) * 16 + hd) * 8192 + l0 + ll;
        *(float2*)&f[o] = make_float2(a0, a1);
    }
}

// ---------------------------------------------------------------------------
// Kernel 2: attention branch.  out = rate1 * out_att.
// f16-packed LDS: kp/vt as __half2, pixel stride 12 dwords (b128-aligned,
// starts 12t%32 tile 8 disjoint 4-bank groups -> conflict-free minimum).
// ---------------------------------------------------------------------------
__global__ __launch_bounds__(512, 4) void att_kernel(
    const float* __restrict__ q, const float* __restrict__ k,
    const float* __restrict__ v,
    const float* __restrict__ wp, const float* __restrict__ bp,
    const float* __restrict__ rate1p, float* __restrict__ out)
{
    __shared__ float kpb[484 * 12];   // 23.2 KB (f16x2 packed)
    __shared__ float vtb[484 * 12];   // 23.2 KB

    int bx = blockIdx.x;          // 8 n * 4 yt * 8 xt = 256
    int xt = bx & 7;
    int yt = (bx >> 3) & 3;
    int n  = bx >> 5;
    int head = n & 3;
    int b    = n >> 2;
    int y0 = yt * 16, x0 = xt * 16;

    for (int e = threadIdx.x; e < 3872; e += 512) {
        int c2 = e & 7;
        int px = e >> 3;
        int ty = px / 22, tx = px % 22;
        int c0 = c2 * 2;
        int sy = y0 + ty - 3; if (sy < 0) sy = -sy; else if (sy >= 64)  sy = 126 - sy;
        int sx = x0 + tx - 3; if (sx < 0) sx = -sx; else if (sx >= 128) sx = 254 - sx;
        int l = sy * 128 + sx;
        size_t o = (size_t)(b * 64 + head * 16 + c0) * 8192 + l;
        float k0 = k[o], k1 = k[o + 8192];
        float v0 = v[o], v1 = v[o + 8192];
        int dd = l >> 10, r2 = l & 1023, ww = r2 >> 5, hh2 = r2 & 31;
        float ld = dd  * (2.0f / 7.0f)  - 1.0f;
        float lw = ww  * (2.0f / 31.0f) - 1.0f;
        float lh = hh2 * (2.0f / 31.0f) - 1.0f;
        float pe0 = bp[c0];
        pe0 = fmaf(wp[c0 * 3 + 0], ld, pe0);
        pe0 = fmaf(wp[c0 * 3 + 1], lw, pe0);
        pe0 = fmaf(wp[c0 * 3 + 2], lh, pe0);
        float pe1 = bp[c0 + 1];
        pe1 = fmaf(wp[c0 * 3 + 3], ld, pe1);
        pe1 = fmaf(wp[c0 * 3 + 4], lw, pe1);
        pe1 = fmaf(wp[c0 * 3 + 5], lh, pe1);
        __half2 hk = __floats2half2_rn(k0 - pe0, k1 - pe1);
        __half2 hv = __floats2half2_rn(v0, v1);
        kpb[px * 12 + c2] = *reinterpret_cast<float*>(&hk);
        vtb[px * 12 + c2] = *reinterpret_cast<float*>(&hv);
    }
    __syncthreads();

    int pix  = threadIdx.x >> 1;      // 0..255
    int part = threadIdx.x & 1;       // channel half
    int tx = pix & 15, ty = pix >> 4;
    int l = (y0 + ty) * 128 + (x0 + tx);
    int cb = part * 8;                // channel base

    float qc[8];
#pragma unroll
    for (int c = 0; c < 8; ++c)
        qc[c] = q[(size_t)(b * 64 + head * 16 + cb + c) * 8192 + l]; // pre-scaled

    float lg[49];
#pragma unroll
    for (int i = 0; i < 7; ++i)
#pragma unroll
        for (int j = 0; j < 7; ++j) {
            float4 r = *(const float4*)&kpb[((ty + i) * 22 + tx + j) * 12
                                            + part * 4];
            float2 u0 = h2f2(r.x), u1 = h2f2(r.y),
                   u2 = h2f2(r.z), u3 = h2f2(r.w);
            float acc =      qc[0] * u0.x;
            acc = fmaf(qc[1], u0.y, acc); acc = fmaf(qc[2], u1.x, acc);
            acc = fmaf(qc[3], u1.y, acc); acc = fmaf(qc[4], u2.x, acc);
            acc = fmaf(qc[5], u2.y, acc); acc = fmaf(qc[6], u3.x, acc);
            acc = fmaf(qc[7], u3.y, acc);
            lg[i * 7 + j] = acc;
        }
#pragma unroll
    for (int kk = 0; kk < 49; ++kk)
        lg[kk] += __shfl_xor(lg[kk], 1, 64);

    float mx = lg[0];
#pragma unroll
    for (int kk = 1; kk < 49; ++kk) mx = fmaxf(mx, lg[kk]);
    float se = 0.f;
#pragma unroll
    for (int kk = 0; kk < 49; ++kk) { lg[kk] = __expf(lg[kk] - mx); se += lg[kk]; }
    float scale = rate1p[0] / se;

    float oc[8];
#pragma unroll
    for (int c = 0; c < 8; ++c) oc[c] = 0.f;
#pragma unroll
    for (int i = 0; i < 7; ++i)
#pragma unroll
        for (int j = 0; j < 7; ++j) {
            float wgt = lg[i * 7 + j];
            float4 r = *(const float4*)&vtb[((ty + i) * 22 + tx + j) * 12
                                            + part * 4];
            float2 u0 = h2f2(r.x), u1 = h2f2(r.y),
                   u2 = h2f2(r.z), u3 = h2f2(r.w);
            oc[0] = fmaf(wgt, u0.x, oc[0]); oc[1] = fmaf(wgt, u0.y, oc[1]);
            oc[2] = fmaf(wgt, u1.x, oc[2]); oc[3] = fmaf(wgt, u1.y, oc[3]);
            oc[4] = fmaf(wgt, u2.x, oc[4]); oc[5] = fmaf(wgt, u2.y, oc[5]);
            oc[6] = fmaf(wgt, u3.x, oc[6]); oc[7] = fmaf(wgt, u3.y, oc[7]);
        }

#pragma unroll
    for (int c = 0; c < 8; ++c)
        out[(size_t)(b * 64 + head * 16 + cb + c) * 8192 + l] = oc[c] * scale;
}

// ---------------------------------------------------------------------------
// Kernel 3: conv branch + combine.  out += rate2 * (depconv(f) + bdep).
// 512 blocks (64-wide x-tiles, ft 19 KB) -> 2 blocks/CU, 8 waves/CU.
// ---------------------------------------------------------------------------
__global__ __launch_bounds__(256) void conv_kernel(
    const float* __restrict__ f,
    const float* __restrict__ wdep, const float* __restrict__ bdep,
    const float* __restrict__ rate2p, float* __restrict__ out)
{
    __shared__ float ft[9][8][66];

    int bx = blockIdx.x;          // 2 b * 16 g * 16 xt = 512
    int xt = bx & 15;
    int g  = (bx >> 4) & 15;
    int b  = bx >> 8;
    int x0 = xt * 64;

    const int NE = 9 * 8 * 66;    // 4752
    for (int e = threadIdx.x; e < NE; e += 256) {
        int xx  = e % 66;
        int rem = e / 66;
        int y = rem % 8, i = rem / 8;
        int gx = x0 + xx - 1;
        float val = 0.f;
        if (gx >= 0 && gx < 1024) {
            int c144 = g * 9 + i;
            val = f[((size_t)(b * 144 + c144)) * 8192 + y * 1024 + gx];
        }
        ft[i][y][xx] = val;
    }
    __syncthreads();

    int xl = threadIdx.x & 63;
    int op = __builtin_amdgcn_readfirstlane(threadIdx.x >> 6); // wave id 0..3
    int o  = g * 4 + op;
    float rate2 = rate2p[0];

    float acc[8];
#pragma unroll
    for (int y = 0; y < 8; ++y) acc[y] = 0.f;

    for (int i = 0; i < 9; ++i) {
        float fr[10][3];
#pragma unroll
        for (int dx = 0; dx < 3; ++dx) { fr[0][dx] = 0.f; fr[9][dx] = 0.f; }
#pragma unroll
        for (int y = 0; y < 8; ++y)
#pragma unroll
            for (int dx = 0; dx < 3; ++dx)
                fr[y + 1][dx] = ft[i][y][xl + dx];
#pragma unroll
        for (int ky = 0; ky < 3; ++ky)
#pragma unroll
            for (int kx = 0; kx < 3; ++kx) {
                float wvv = wdep[((o * 9 + i) * 3 + ky) * 3 + kx];
#pragma unroll
                for (int y = 0; y < 8; ++y)
                    acc[y] = fmaf(wvv, fr[y + ky][kx], acc[y]);
            }
    }

    float bd = bdep[o];
#pragma unroll
    for (int y = 0; y < 8; ++y) {
        size_t idx = (size_t)(b * 64 + o) * 8192 + y * 1024 + x0 + xl;
        out[idx] = out[idx] + rate2 * (acc[y] + bd);
    }
}

// ---------------------------------------------------------------------------
extern "C" void kernel_launch(void* const* d_in, const int* in_sizes, int n_in,
                              void* d_out, int out_size, void* d_ws, size_t ws_size,
                              hipStream_t stream)
{
    (void)in_sizes; (void)n_in; (void)out_size; (void)ws_size;
    const float* x     = (const float*)d_in[0];
    const float* w1    = (const float*)d_in[1];
    const float* b1    = (const float*)d_in[2];
    const float* w2    = (const float*)d_in[3];
    const float* b2    = (const float*)d_in[4];
    const float* w3    = (const float*)d_in[5];
    const float* b3    = (const float*)d_in[6];
    const float* wp    = (const float*)d_in[7];
    const float* bp    = (const float*)d_in[8];
    const float* wfc   = (const float*)d_in[9];
    const float* wdep  = (const float*)d_in[10];
    const float* bdep  = (const float*)d_in[11];
    const float* rate1 = (const float*)d_in[12];
    const float* rate2 = (const float*)d_in[13];
    float* out = (float*)d_out;

    float* wsf = (float*)d_ws;
    float* q = wsf;                 // 3 x 1,048,576 floats (q,k,v)
    float* k = wsf + 1048576;
    float* v = wsf + 2097152;
    float* f = wsf + 3145728;       // 2,359,296 floats

    qkvf_kernel<<<256, 512, 0, stream>>>(x, w1, b1, w2, b2, w3, b3, wfc,
                                         q, k, v, f);
    att_kernel <<<256, 512, 0, stream>>>(q, k, v, wp, bp, rate1, out);
    conv_kernel<<<512, 256, 0, stream>>>(f, wdep, bdep, rate2, out);
}